// Round 2
// baseline (3657.894 us; speedup 1.0000x reference)
//
#include <hip/hip_runtime.h>

// ---------------- problem constants ----------------
#define T_STEPS 128
#define N_B     512
#define D_IN    1024
#define H_DIM   1024
#define G_DIM   3072        // 3*H
#define CHUNK   8           // timesteps per xp-GEMM chunk
#define NCHUNK  16
#define M_CHUNK (CHUNK * N_B)   // 4096 rows per xp-GEMM chunk

typedef short          s8v  __attribute__((ext_vector_type(8)));   // 8 bf16 (4 VGPR)
typedef float          f4v  __attribute__((ext_vector_type(4)));
typedef unsigned short u4v  __attribute__((ext_vector_type(4)));

__device__ __forceinline__ unsigned short f2bf(float f) {
  union { float f; unsigned u; } v; v.f = f;
  unsigned r = v.u + 0x7FFFu + ((v.u >> 16) & 1u);   // RNE
  return (unsigned short)(r >> 16);
}
__device__ __forceinline__ float bf2f(unsigned short h) {
  union { unsigned u; float f; } v; v.u = ((unsigned)h) << 16;
  return v.f;
}
__device__ __forceinline__ void async16(const void* g, void* l) {
  __builtin_amdgcn_global_load_lds(
      (const __attribute__((address_space(1))) unsigned*)g,
      (__attribute__((address_space(3))) unsigned*)l, 16, 0, 0);
}
__device__ __forceinline__ float sigmoidf_(float x) { return 1.f / (1.f + __expf(-x)); }
__device__ __forceinline__ float tanhf_(float x)    { return 1.f - 2.f / (1.f + __expf(2.f * x)); }

// ---------------- f32 -> bf16 conversion (vectorized, grid-stride) ----------------
__global__ void cvt_bf16(const float* __restrict__ in, unsigned short* __restrict__ out, long n4) {
  long i = (long)blockIdx.x * blockDim.x + threadIdx.x;
  long stride = (long)gridDim.x * blockDim.x;
  for (; i < n4; i += stride) {
    f4v v = *(const f4v*)(in + i * 4);
    u4v o;
    #pragma unroll
    for (int e = 0; e < 4; ++e) o[e] = f2bf(v[e]);
    *(u4v*)(out + i * 4) = o;
  }
}

// ---------------- reset[t] = (t==0) || any(m[t,:]==1.0) ----------------
__global__ void reset_kernel(const float* __restrict__ masks, int* __restrict__ reset) {
  const int t = blockIdx.x;
  __shared__ int flag;
  if (threadIdx.x == 0) flag = (t == 0) ? 1 : 0;
  __syncthreads();
  if (t > 0 && masks[(size_t)t * N_B + threadIdx.x] == 1.0f) flag = 1;  // benign same-value race
  __syncthreads();
  if (threadIdx.x == 0) reset[t] = flag;
}

// ---------------- xp chunk GEMM: C[m][g] = sum_k A[m][k]*B[g][k] + bias[g] ----------------
// A: x chunk bf16 [M_CHUNK][1024], B: W_ih bf16 [3072][1024], C: bf16 [M_CHUNK][3072]
__global__ __launch_bounds__(256) void gemm_xp(const unsigned short* __restrict__ A,
                                               const unsigned short* __restrict__ B,
                                               const float* __restrict__ bias,
                                               unsigned short* __restrict__ C) {
  const int m0 = blockIdx.y * 128, g0 = blockIdx.x * 128;
  const int tid = threadIdx.x, wv = tid >> 6, l = tid & 63;
  const int l15 = l & 15, l4 = l >> 4;
  const int wr = wv >> 1, wc = wv & 1;
  __shared__ unsigned short As[128 * 64], Bs[128 * 64];

  f4v zero4 = {0.f, 0.f, 0.f, 0.f};
  f4v acc[4][4];
  #pragma unroll
  for (int i = 0; i < 4; ++i)
    #pragma unroll
    for (int j = 0; j < 4; ++j) acc[i][j] = zero4;

  const int srow = l >> 3;          // 0..7 within 8-row segment
  const int selem = (l & 7) * 8;    // element offset within 64-wide K slab

  for (int kt = 0; kt < 1024; kt += 64) {
    #pragma unroll
    for (int cc = 0; cc < 4; ++cc) {
      int s = wv * 4 + cc;                    // 16 segments of 8 rows
      int row = s * 8 + srow;
      async16(A + (size_t)(m0 + row) * 1024 + kt + selem, &As[s * 512]);
      async16(B + (size_t)(g0 + row) * 1024 + kt + selem, &Bs[s * 512]);
    }
    __syncthreads();
    #pragma unroll
    for (int ks = 0; ks < 2; ++ks) {
      s8v a[4], b[4];
      #pragma unroll
      for (int i = 0; i < 4; ++i) {
        a[i] = *(const s8v*)&As[(wr * 64 + i * 16 + l15) * 64 + ks * 32 + l4 * 8];
        b[i] = *(const s8v*)&Bs[(wc * 64 + i * 16 + l15) * 64 + ks * 32 + l4 * 8];
      }
      #pragma unroll
      for (int i = 0; i < 4; ++i)
        #pragma unroll
        for (int j = 0; j < 4; ++j)
          acc[i][j] = __builtin_amdgcn_mfma_f32_16x16x32_bf16(a[i], b[j], acc[i][j], 0, 0, 0);
    }
    __syncthreads();
  }
  #pragma unroll
  for (int j = 0; j < 4; ++j) {
    int gcol = g0 + wc * 64 + j * 16 + l15;
    float bv = bias[gcol];
    #pragma unroll
    for (int i = 0; i < 4; ++i) {
      int mrow = m0 + wr * 64 + i * 16 + l4 * 4;
      #pragma unroll
      for (int r = 0; r < 4; ++r)
        C[(size_t)(mrow + r) * G_DIM + gcol] = f2bf(acc[i][j][r] + bv);
    }
  }
}

// ---------------- one GRU timestep (grid-wide sync = kernel boundary) ----------------
// Grid (16 j-tiles, 16 n-tiles) = 256 blocks, 256 threads (4 waves).
// Block (jt, nt): rows n0..n0+31, output cols j0..j0+63 for ALL 3 gates.
// hp = h @ W_hh^T computed with MFMA over K=1024 in 64-wide slabs; gates fused.
__global__ __launch_bounds__(256) void gru_step(
    const unsigned short* __restrict__ Whh,   // [3072][1024] bf16
    const unsigned short* __restrict__ xp,    // chunk base [CHUNK*512][3072] bf16 (+b_ih)
    const float* __restrict__ masks,          // [T*N]
    const int* __restrict__ reset,            // [T]
    const float* __restrict__ bhh,            // [3072]
    const float* __restrict__ hxs,            // [512][1024] initial h (f32)
    const unsigned short* __restrict__ hread, // bf16 h_prev [512][1024]
    unsigned short* __restrict__ hwrite,      // bf16 h_new  [512][1024]
    float* __restrict__ y,                    // [T*N][1024]
    float* __restrict__ hlast,                // [512][1024]
    int t, int ls) {
  const int jt = blockIdx.x, nt = blockIdx.y;
  const int j0 = jt * 64, n0 = nt * 32;
  const int tid = threadIdx.x, w = tid >> 6, l = tid & 63;
  const int l15 = l & 15, l4 = l >> 4;

  __shared__ unsigned short Asl[32 * 64];     // 4 KB   (h slab)
  __shared__ unsigned short Bsl[192 * 64];    // 24 KB  (W_hh slab: 3 gates x 64 cols)
  __shared__ float hp[192 * 33];              // 25.3 KB (hp, col-major padded)

  const int rst = reset[t];
  const float mva = masks[(size_t)t * N_B + n0 + l15];
  const float mvb = masks[(size_t)t * N_B + n0 + 16 + l15];
  const bool zo0 = rst && (mva == 0.0f);
  const bool zo1 = rst && (mvb == 0.0f);

  f4v zero4 = {0.f, 0.f, 0.f, 0.f};
  s8v zer8 = {0, 0, 0, 0, 0, 0, 0, 0};
  f4v acc[2][3];
  #pragma unroll
  for (int i = 0; i < 2; ++i)
    #pragma unroll
    for (int j = 0; j < 3; ++j) acc[i][j] = zero4;

  const int srow = l >> 3;           // 0..7
  const int selem = (l & 7) * 8;     // 0..56

  for (int kt = 0; kt < 1024; kt += 64) {
    // stage A rows: wave w loads rows [w*8, w*8+8)
    {
      int r = w * 8 + srow;
      async16(hread + (size_t)(n0 + r) * H_DIM + kt + selem, &Asl[(w * 8) * 64]);
    }
    // stage B rows: wave w loads rows [w*48, w*48+48) in 6 issues of 8 rows
    #pragma unroll
    for (int q = 0; q < 6; ++q) {
      int r = w * 48 + q * 8 + srow;                       // 0..191 (per-lane)
      int wrow = (r >> 6) * H_DIM + j0 + (r & 63);         // W_hh row = gate*1024 + j
      async16(Whh + (size_t)wrow * H_DIM + kt + selem, &Bsl[(w * 48 + q * 8) * 64]);
    }
    __syncthreads();
    #pragma unroll
    for (int ks = 0; ks < 2; ++ks) {
      s8v a[2], b[3];
      a[0] = *(const s8v*)&Asl[(l15) * 64 + ks * 32 + l4 * 8];
      a[1] = *(const s8v*)&Asl[(16 + l15) * 64 + ks * 32 + l4 * 8];
      if (zo0) a[0] = zer8;
      if (zo1) a[1] = zer8;
      #pragma unroll
      for (int j = 0; j < 3; ++j)
        b[j] = *(const s8v*)&Bsl[(w * 48 + j * 16 + l15) * 64 + ks * 32 + l4 * 8];
      #pragma unroll
      for (int i = 0; i < 2; ++i)
        #pragma unroll
        for (int j = 0; j < 3; ++j)
          acc[i][j] = __builtin_amdgcn_mfma_f32_16x16x32_bf16(a[i], b[j], acc[i][j], 0, 0, 0);
    }
    __syncthreads();
  }

  // write hp to LDS: col = B-slab row index (gate*64 + c), row = n-within-32
  #pragma unroll
  for (int i = 0; i < 2; ++i)
    #pragma unroll
    for (int j = 0; j < 3; ++j) {
      int col = w * 48 + j * 16 + l15;
      int rowb = i * 16 + l4 * 4;
      #pragma unroll
      for (int r = 0; r < 4; ++r)
        hp[col * 33 + rowb + r] = acc[i][j][r];
    }
  __syncthreads();

  // gates: thread handles j = tid&63 and 8 n-rows
  const int jl = tid & 63;
  const int ng = tid >> 6;
  const float br = bhh[0 * H_DIM + j0 + jl];
  const float bz = bhh[1 * H_DIM + j0 + jl];
  const float bn = bhh[2 * H_DIM + j0 + jl];
  const unsigned short* xpt = xp + (size_t)ls * N_B * G_DIM;
  #pragma unroll
  for (int p = 0; p < 8; ++p) {
    const int nl = ng * 8 + p;
    const int n = n0 + nl;
    const float m = masks[(size_t)t * N_B + n];
    float hprev = (t == 0) ? hxs[(size_t)n * H_DIM + j0 + jl]
                           : y[((size_t)(t - 1) * N_B + n) * H_DIM + j0 + jl];
    if (rst && m == 0.0f) hprev = 0.0f;
    const float hr = hp[(0 * 64 + jl) * 33 + nl] + br;
    const float hz = hp[(1 * 64 + jl) * 33 + nl] + bz;
    const float hn = hp[(2 * 64 + jl) * 33 + nl] + bn;
    const size_t xoff = (size_t)n * G_DIM + j0 + jl;
    const float xr = bf2f(xpt[xoff]);
    const float xz = bf2f(xpt[xoff + 1024]);
    const float xn = bf2f(xpt[xoff + 2048]);
    const float rg = sigmoidf_(xr + hr);
    const float zg = sigmoidf_(xz + hz);
    const float ngt = tanhf_(xn + rg * hn);
    const float hnew = (1.f - zg) * ngt + zg * hprev;
    const size_t gidx = (size_t)n * H_DIM + j0 + jl;
    y[((size_t)t * N_B) * H_DIM + gidx] = hnew;
    hwrite[gidx] = f2bf(hnew);
    if (t == T_STEPS - 1) hlast[gidx] = hnew;
  }
}

// ---------------- final LayerNorm over y rows (in place) ----------------
__global__ __launch_bounds__(256) void ln_kernel(float* __restrict__ y,
                                                 const float* __restrict__ gamma,
                                                 const float* __restrict__ beta) {
  const size_t row = blockIdx.x;
  float* p = y + row * (size_t)H_DIM;
  const int tid = threadIdx.x;
  f4v v = *(const f4v*)(p + tid * 4);
  float s = v[0] + v[1] + v[2] + v[3];
  float q = v[0] * v[0] + v[1] * v[1] + v[2] * v[2] + v[3] * v[3];
  #pragma unroll
  for (int off = 32; off > 0; off >>= 1) {
    s += __shfl_down(s, off);
    q += __shfl_down(q, off);
  }
  __shared__ float sb[8];
  const int wid = tid >> 6, lid = tid & 63;
  if (lid == 0) { sb[wid] = s; sb[4 + wid] = q; }
  __syncthreads();
  float S = sb[0] + sb[1] + sb[2] + sb[3];
  float Q = sb[4] + sb[5] + sb[6] + sb[7];
  float mean = S * (1.f / H_DIM);
  float var = Q * (1.f / H_DIM) - mean * mean;
  float inv = rsqrtf(var + 1e-5f);
  f4v g4 = *(const f4v*)(gamma + tid * 4);
  f4v b4 = *(const f4v*)(beta + tid * 4);
  f4v o;
  #pragma unroll
  for (int e = 0; e < 4; ++e) o[e] = (v[e] - mean) * inv * g4[e] + b4[e];
  *(f4v*)(p + tid * 4) = o;
}

// ---------------- host ----------------
extern "C" void kernel_launch(void* const* d_in, const int* in_sizes, int n_in,
                              void* d_out, int out_size, void* d_ws, size_t ws_size,
                              hipStream_t stream) {
  const float* x     = (const float*)d_in[0];
  const float* hxs   = (const float*)d_in[1];
  const float* masks = (const float*)d_in[2];
  const float* W_ih  = (const float*)d_in[3];
  const float* W_hh  = (const float*)d_in[4];
  const float* b_ih  = (const float*)d_in[5];
  const float* b_hh  = (const float*)d_in[6];
  const float* gamma = (const float*)d_in[7];
  const float* beta  = (const float*)d_in[8];
  float* y = (float*)d_out;                                 // [65536][1024]
  float* hlast = y + (size_t)T_STEPS * N_B * H_DIM;         // [512][1024]

  char* ws = (char*)d_ws;
  unsigned short* Wih_bf = (unsigned short*)ws;  ws += (size_t)G_DIM * D_IN * 2;       // 6.3 MB
  unsigned short* Whh_bf = (unsigned short*)ws;  ws += (size_t)G_DIM * H_DIM * 2;      // 6.3 MB
  unsigned short* xc_bf  = (unsigned short*)ws;  ws += (size_t)M_CHUNK * D_IN * 2;     // 8.4 MB
  unsigned short* xp_bf  = (unsigned short*)ws;  ws += (size_t)M_CHUNK * G_DIM * 2;    // 25.2 MB
  unsigned short* hbuf   = (unsigned short*)ws;  ws += (size_t)2 * N_B * H_DIM * 2;    // 2.1 MB
  int* reset             = (int*)ws;             ws += 512;

  cvt_bf16<<<1024, 256, 0, stream>>>(W_ih, Wih_bf, (long)G_DIM * D_IN / 4);
  cvt_bf16<<<1024, 256, 0, stream>>>(W_hh, Whh_bf, (long)G_DIM * H_DIM / 4);
  cvt_bf16<<<512, 256, 0, stream>>>(hxs, hbuf, (long)N_B * H_DIM / 4);   // hbuf[0] = bf16(h0)
  reset_kernel<<<128, 512, 0, stream>>>(masks, reset);

  const size_t NH = (size_t)N_B * H_DIM;
  for (int ck = 0; ck < NCHUNK; ++ck) {
    const float* xck = x + (size_t)ck * M_CHUNK * D_IN;
    cvt_bf16<<<2048, 256, 0, stream>>>(xck, xc_bf, (long)M_CHUNK * D_IN / 4);
    dim3 gg(G_DIM / 128, M_CHUNK / 128);   // (24, 32)
    gemm_xp<<<gg, 256, 0, stream>>>(xc_bf, Wih_bf, b_ih, xp_bf);

    for (int ls = 0; ls < CHUNK; ++ls) {
      const int t = ck * CHUNK + ls;
      const unsigned short* hread = hbuf + (size_t)(t & 1) * NH;
      unsigned short* hwrite = hbuf + (size_t)((t & 1) ^ 1) * NH;
      gru_step<<<dim3(16, 16), 256, 0, stream>>>(Whh_bf, xp_bf, masks, reset, b_hh,
                                                 hxs, hread, hwrite, y, hlast, t, ls);
    }
  }

  ln_kernel<<<T_STEPS * N_B, 256, 0, stream>>>(y, gamma, beta);
}

// Round 3
// 2752.905 us; speedup vs baseline: 1.3287x; 1.3287x over previous
//
#include <hip/hip_runtime.h>

// ---------------- problem constants ----------------
#define T_STEPS 128
#define N_B     512
#define D_IN    1024
#define H_DIM   1024
#define G_DIM   3072        // 3*H
#define CHUNK   8           // timesteps per xp-GEMM chunk
#define NCHUNK  16
#define M_CHUNK (CHUNK * N_B)   // 4096 rows per xp-GEMM chunk

typedef short          s8v  __attribute__((ext_vector_type(8)));   // 8 bf16 (4 VGPR)
typedef float          f4v  __attribute__((ext_vector_type(4)));
typedef unsigned short u4v  __attribute__((ext_vector_type(4)));

__device__ __forceinline__ unsigned short f2bf(float f) {
  union { float f; unsigned u; } v; v.f = f;
  unsigned r = v.u + 0x7FFFu + ((v.u >> 16) & 1u);   // RNE
  return (unsigned short)(r >> 16);
}
__device__ __forceinline__ float bf2f(unsigned short h) {
  union { unsigned u; float f; } v; v.u = ((unsigned)h) << 16;
  return v.f;
}
__device__ __forceinline__ void async16(const void* g, void* l) {
  __builtin_amdgcn_global_load_lds(
      (const __attribute__((address_space(1))) unsigned*)g,
      (__attribute__((address_space(3))) unsigned*)l, 16, 0, 0);
}
__device__ __forceinline__ float sigmoidf_(float x) { return 1.f / (1.f + __expf(-x)); }
__device__ __forceinline__ float tanhf_(float x)    { return 1.f - 2.f / (1.f + __expf(2.f * x)); }

// ---------------- f32 -> bf16 conversion (vectorized, grid-stride) ----------------
__global__ void cvt_bf16(const float* __restrict__ in, unsigned short* __restrict__ out, long n4) {
  long i = (long)blockIdx.x * blockDim.x + threadIdx.x;
  long stride = (long)gridDim.x * blockDim.x;
  for (; i < n4; i += stride) {
    f4v v = *(const f4v*)(in + i * 4);
    u4v o;
    #pragma unroll
    for (int e = 0; e < 4; ++e) o[e] = f2bf(v[e]);
    *(u4v*)(out + i * 4) = o;
  }
}

// ---------------- reset[t] = (t==0) || any(m[t,:]==1.0) ----------------
__global__ void reset_kernel(const float* __restrict__ masks, int* __restrict__ reset) {
  const int t = blockIdx.x;
  __shared__ int flag;
  if (threadIdx.x == 0) flag = (t == 0) ? 1 : 0;
  __syncthreads();
  if (t > 0 && masks[(size_t)t * N_B + threadIdx.x] == 1.0f) flag = 1;  // benign same-value race
  __syncthreads();
  if (threadIdx.x == 0) reset[t] = flag;
}

// ---------------- xp chunk GEMM: C[m][g] = sum_k A[m][k]*B[g][k] + bias[g] ----------------
// A: x chunk bf16 [M_CHUNK][1024], B: W_ih bf16 [3072][1024], C: bf16 [M_CHUNK][3072]
__global__ __launch_bounds__(256) void gemm_xp(const unsigned short* __restrict__ A,
                                               const unsigned short* __restrict__ B,
                                               const float* __restrict__ bias,
                                               unsigned short* __restrict__ C) {
  const int m0 = blockIdx.y * 128, g0 = blockIdx.x * 128;
  const int tid = threadIdx.x, wv = tid >> 6, l = tid & 63;
  const int l15 = l & 15, l4 = l >> 4;
  const int wr = wv >> 1, wc = wv & 1;
  __shared__ unsigned short As[128 * 64], Bs[128 * 64];

  f4v zero4 = {0.f, 0.f, 0.f, 0.f};
  f4v acc[4][4];
  #pragma unroll
  for (int i = 0; i < 4; ++i)
    #pragma unroll
    for (int j = 0; j < 4; ++j) acc[i][j] = zero4;

  const int srow = l >> 3;          // 0..7 within 8-row segment
  const int selem = (l & 7) * 8;    // element offset within 64-wide K slab

  for (int kt = 0; kt < 1024; kt += 64) {
    #pragma unroll
    for (int cc = 0; cc < 4; ++cc) {
      int s = wv * 4 + cc;                    // 16 segments of 8 rows
      int row = s * 8 + srow;
      async16(A + (size_t)(m0 + row) * 1024 + kt + selem, &As[s * 512]);
      async16(B + (size_t)(g0 + row) * 1024 + kt + selem, &Bs[s * 512]);
    }
    __syncthreads();
    #pragma unroll
    for (int ks = 0; ks < 2; ++ks) {
      s8v a[4], b[4];
      #pragma unroll
      for (int i = 0; i < 4; ++i) {
        a[i] = *(const s8v*)&As[(wr * 64 + i * 16 + l15) * 64 + ks * 32 + l4 * 8];
        b[i] = *(const s8v*)&Bs[(wc * 64 + i * 16 + l15) * 64 + ks * 32 + l4 * 8];
      }
      #pragma unroll
      for (int i = 0; i < 4; ++i)
        #pragma unroll
        for (int j = 0; j < 4; ++j)
          acc[i][j] = __builtin_amdgcn_mfma_f32_16x16x32_bf16(a[i], b[j], acc[i][j], 0, 0, 0);
    }
    __syncthreads();
  }
  #pragma unroll
  for (int j = 0; j < 4; ++j) {
    int gcol = g0 + wc * 64 + j * 16 + l15;
    float bv = bias[gcol];
    #pragma unroll
    for (int i = 0; i < 4; ++i) {
      int mrow = m0 + wr * 64 + i * 16 + l4 * 4;
      #pragma unroll
      for (int r = 0; r < 4; ++r)
        C[(size_t)(mrow + r) * G_DIM + gcol] = f2bf(acc[i][j][r] + bv);
    }
  }
}

// ---------------- one GRU timestep, v2 ----------------
// Grid: 256 blocks, 1D. jt = bid & 31 (32 j-slices of 32), nt = bid >> 5 (8 n-slices of 64).
//   -> bid % 8 == jt % 8: all 8 n-tiles of a jt land on ONE XCD; its W slice (768KB) stays L2-hot.
// Block: 64 n-rows x 32 j-cols x 3 gates, gates in-register (identical lane->(n,j) map for r/z/n).
// K staged in 4 chunks of 256; LDS 80KB; T2 XOR swizzle (byte ^= (row&7)<<4) on both sides.
__global__ __launch_bounds__(256) void gru_step(
    const unsigned short* __restrict__ Whh,   // [3072][1024] bf16
    const unsigned short* __restrict__ xp,    // chunk base [CHUNK*512][3072] bf16 (+b_ih)
    const float* __restrict__ masks,          // [T*N]
    const int* __restrict__ reset,            // [T]
    const float* __restrict__ bhh,            // [3072]
    const float* __restrict__ hxs,            // [512][1024] initial h (f32)
    const unsigned short* __restrict__ hread, // bf16 h_prev [512][1024]
    unsigned short* __restrict__ hwrite,      // bf16 h_new  [512][1024]
    float* __restrict__ y,                    // [T*N][1024]
    float* __restrict__ hlast,                // [512][1024]
    int t, int ls) {
  const int bid = blockIdx.x;
  const int jt = bid & 31, nt = bid >> 5;
  const int j0 = jt * 32, n0 = nt * 64;
  const int tid = threadIdx.x, w = tid >> 6, l = tid & 63;
  const int l15 = l & 15, l4 = l >> 4;
  const int wn = w & 1, wj = w >> 1;         // wave -> (n-half of 32, jj-half of 16)
  const int l5 = l & 31, lh = l >> 5;        // staging lane split: 32 lanes/row

  __shared__ unsigned short Hs[64 * 256];    // 32 KB h slab   [row][256k] (swizzled)
  __shared__ unsigned short Ws[96 * 256];    // 48 KB W slab   [gate*32+jj][256k] (swizzled)

  const int rst = reset[t];
  // MFMA-row masks (A rows): row rr = wn*32 + i*16 + l15
  bool zo[2];
  #pragma unroll
  for (int i = 0; i < 2; ++i) {
    float mv = masks[(size_t)t * N_B + n0 + wn * 32 + i * 16 + l15];
    zo[i] = rst && (mv == 0.0f);
  }

  f4v zero4 = {0.f, 0.f, 0.f, 0.f};
  s8v zer8 = {0, 0, 0, 0, 0, 0, 0, 0};
  f4v acc[2][3];                              // [n-sub][gate]
  #pragma unroll
  for (int i = 0; i < 2; ++i)
    #pragma unroll
    for (int g = 0; g < 3; ++g) acc[i][g] = zero4;

  const int swz_rd = (l15 & 7) << 4;          // read-side row-XOR (rr&7 == l15&7 for all frags)

  for (int kt = 0; kt < 1024; kt += 256) {
    // ---- stage h slab: 8 issues x 8 rows (pre-swizzled global source) ----
    #pragma unroll
    for (int q = 0; q < 8; ++q) {
      int rr = q * 8 + w * 2 + lh;                        // 0..63
      int kb = (l5 * 16) ^ ((rr & 7) << 4);               // byte within 512B row
      async16(hread + (size_t)(n0 + rr) * H_DIM + kt + (kb >> 1), &Hs[(q * 8 + w * 2) * 256]);
    }
    // ---- stage W slab: 12 issues x 8 rows; row rr = gate*32 + jj_local ----
    #pragma unroll
    for (int q = 0; q < 12; ++q) {
      int rr = q * 8 + w * 2 + lh;                        // 0..95
      int gate = rr >> 5, jjl = rr & 31;
      int kb = (l5 * 16) ^ ((rr & 7) << 4);
      async16(Whh + ((size_t)gate * H_DIM + j0 + jjl) * H_DIM + kt + (kb >> 1),
              &Ws[(q * 8 + w * 2) * 256]);
    }
    __syncthreads();
    // ---- MFMA: 8 K-steps of 32 ----
    #pragma unroll
    for (int ks = 0; ks < 8; ++ks) {
      const int kbb = (ks * 64 + l4 * 16) ^ swz_rd;       // swizzled byte offset in row
      s8v a[2], b[3];
      #pragma unroll
      for (int i = 0; i < 2; ++i) {
        int rr = wn * 32 + i * 16 + l15;
        a[i] = *(const s8v*)((const char*)Hs + rr * 512 + kbb);
        if (zo[i]) a[i] = zer8;
      }
      #pragma unroll
      for (int g = 0; g < 3; ++g) {
        int rr = g * 32 + wj * 16 + l15;
        b[g] = *(const s8v*)((const char*)Ws + rr * 512 + kbb);
      }
      #pragma unroll
      for (int i = 0; i < 2; ++i)
        #pragma unroll
        for (int g = 0; g < 3; ++g)
          acc[i][g] = __builtin_amdgcn_mfma_f32_16x16x32_bf16(a[i], b[g], acc[i][g], 0, 0, 0);
    }
    __syncthreads();
  }

  // ---- gates fully in-register: lane holds matching (hr,hz,hn) per (n,jj) ----
  const int jj = j0 + wj * 16 + l15;                      // this lane's j column
  const float br = bhh[jj];
  const float bz = bhh[H_DIM + jj];
  const float bn = bhh[2 * H_DIM + jj];
  const float* hsrc = (t == 0) ? hxs : (y + (size_t)(t - 1) * N_B * H_DIM);
  const unsigned short* xpt = xp + (size_t)ls * N_B * G_DIM;

  #pragma unroll
  for (int i = 0; i < 2; ++i) {
    #pragma unroll
    for (int r = 0; r < 4; ++r) {
      const int n = n0 + wn * 32 + i * 16 + l4 * 4 + r;
      const float m = masks[(size_t)t * N_B + n];
      float hprev = hsrc[(size_t)n * H_DIM + jj];
      if (rst && m == 0.0f) hprev = 0.0f;
      const float hr = acc[i][0][r] + br;
      const float hz = acc[i][1][r] + bz;
      const float hn = acc[i][2][r] + bn;
      const size_t xo = (size_t)n * G_DIM + jj;
      const float xr = bf2f(xpt[xo]);
      const float xz = bf2f(xpt[xo + H_DIM]);
      const float xn = bf2f(xpt[xo + 2 * H_DIM]);
      const float rg = sigmoidf_(xr + hr);
      const float zg = sigmoidf_(xz + hz);
      const float ng = tanhf_(xn + rg * hn);
      const float hnew = (1.f - zg) * ng + zg * hprev;
      const size_t gidx = (size_t)n * H_DIM + jj;
      y[(size_t)t * N_B * H_DIM + gidx] = hnew;
      hwrite[gidx] = f2bf(hnew);
      if (t == T_STEPS - 1) hlast[gidx] = hnew;
    }
  }
}

// ---------------- final LayerNorm over y rows (in place) ----------------
__global__ __launch_bounds__(256) void ln_kernel(float* __restrict__ y,
                                                 const float* __restrict__ gamma,
                                                 const float* __restrict__ beta) {
  const size_t row = blockIdx.x;
  float* p = y + row * (size_t)H_DIM;
  const int tid = threadIdx.x;
  f4v v = *(const f4v*)(p + tid * 4);
  float s = v[0] + v[1] + v[2] + v[3];
  float q = v[0] * v[0] + v[1] * v[1] + v[2] * v[2] + v[3] * v[3];
  #pragma unroll
  for (int off = 32; off > 0; off >>= 1) {
    s += __shfl_down(s, off);
    q += __shfl_down(q, off);
  }
  __shared__ float sb[8];
  const int wid = tid >> 6, lid = tid & 63;
  if (lid == 0) { sb[wid] = s; sb[4 + wid] = q; }
  __syncthreads();
  float S = sb[0] + sb[1] + sb[2] + sb[3];
  float Q = sb[4] + sb[5] + sb[6] + sb[7];
  float mean = S * (1.f / H_DIM);
  float var = Q * (1.f / H_DIM) - mean * mean;
  float inv = rsqrtf(var + 1e-5f);
  f4v g4 = *(const f4v*)(gamma + tid * 4);
  f4v b4 = *(const f4v*)(beta + tid * 4);
  f4v o;
  #pragma unroll
  for (int e = 0; e < 4; ++e) o[e] = (v[e] - mean) * inv * g4[e] + b4[e];
  *(f4v*)(p + tid * 4) = o;
}

// ---------------- host ----------------
extern "C" void kernel_launch(void* const* d_in, const int* in_sizes, int n_in,
                              void* d_out, int out_size, void* d_ws, size_t ws_size,
                              hipStream_t stream) {
  const float* x     = (const float*)d_in[0];
  const float* hxs   = (const float*)d_in[1];
  const float* masks = (const float*)d_in[2];
  const float* W_ih  = (const float*)d_in[3];
  const float* W_hh  = (const float*)d_in[4];
  const float* b_ih  = (const float*)d_in[5];
  const float* b_hh  = (const float*)d_in[6];
  const float* gamma = (const float*)d_in[7];
  const float* beta  = (const float*)d_in[8];
  float* y = (float*)d_out;                                 // [65536][1024]
  float* hlast = y + (size_t)T_STEPS * N_B * H_DIM;         // [512][1024]

  char* ws = (char*)d_ws;
  unsigned short* Wih_bf = (unsigned short*)ws;  ws += (size_t)G_DIM * D_IN * 2;       // 6.3 MB
  unsigned short* Whh_bf = (unsigned short*)ws;  ws += (size_t)G_DIM * H_DIM * 2;      // 6.3 MB
  unsigned short* xc_bf  = (unsigned short*)ws;  ws += (size_t)M_CHUNK * D_IN * 2;     // 8.4 MB
  unsigned short* xp_bf  = (unsigned short*)ws;  ws += (size_t)M_CHUNK * G_DIM * 2;    // 25.2 MB
  unsigned short* hbuf   = (unsigned short*)ws;  ws += (size_t)2 * N_B * H_DIM * 2;    // 2.1 MB
  int* reset             = (int*)ws;             ws += 512;

  cvt_bf16<<<1024, 256, 0, stream>>>(W_ih, Wih_bf, (long)G_DIM * D_IN / 4);
  cvt_bf16<<<1024, 256, 0, stream>>>(W_hh, Whh_bf, (long)G_DIM * H_DIM / 4);
  cvt_bf16<<<512, 256, 0, stream>>>(hxs, hbuf, (long)N_B * H_DIM / 4);   // hbuf[0] = bf16(h0)
  reset_kernel<<<128, 512, 0, stream>>>(masks, reset);

  const size_t NH = (size_t)N_B * H_DIM;
  for (int ck = 0; ck < NCHUNK; ++ck) {
    const float* xck = x + (size_t)ck * M_CHUNK * D_IN;
    cvt_bf16<<<2048, 256, 0, stream>>>(xck, xc_bf, (long)M_CHUNK * D_IN / 4);
    dim3 gg(G_DIM / 128, M_CHUNK / 128);   // (24, 32)
    gemm_xp<<<gg, 256, 0, stream>>>(xc_bf, Wih_bf, b_ih, xp_bf);

    for (int ls = 0; ls < CHUNK; ++ls) {
      const int t = ck * CHUNK + ls;
      const unsigned short* hread = hbuf + (size_t)(t & 1) * NH;
      unsigned short* hwrite = hbuf + (size_t)((t & 1) ^ 1) * NH;
      gru_step<<<256, 256, 0, stream>>>(Whh_bf, xp_bf, masks, reset, b_hh,
                                        hxs, hread, hwrite, y, hlast, t, ls);
    }
  }

  ln_kernel<<<T_STEPS * N_B, 256, 0, stream>>>(y, gamma, beta);
}